// Round 1
// baseline (1016.256 us; speedup 1.0000x reference)
//
#include <hip/hip_runtime.h>

#define Bsz 1024
#define Tt  256
#define Vv  32004
#define Dd  50
#define Hh  64

// ---------------------------------------------------------------------------
// Prologue: tab[v][g] = sum_d emb[v][d] * Wih[g][d] + bih[g] + bhh[g]
// for both LSTMs. One block per vocab row, thread g = gate index (0..255).
// ---------------------------------------------------------------------------
__global__ void build_tables(const float* __restrict__ emb,
                             const float* __restrict__ Wih1,
                             const float* __restrict__ bih1,
                             const float* __restrict__ bhh1,
                             const float* __restrict__ Wih2,
                             const float* __restrict__ bih2,
                             const float* __restrict__ bhh2,
                             float* __restrict__ tab1,
                             float* __restrict__ tab2) {
    const int v = blockIdx.x;
    const int g = threadIdx.x;           // 0..255
    float a1 = bih1[g] + bhh1[g];
    float a2 = bih2[g] + bhh2[g];
    const float* e  = emb  + (size_t)v * Dd;
    const float* w1 = Wih1 + (size_t)g * Dd;
    const float* w2 = Wih2 + (size_t)g * Dd;
#pragma unroll
    for (int d = 0; d < Dd; ++d) {
        const float ev = e[d];           // broadcast across the wave
        a1 += ev * w1[d];
        a2 += ev * w2[d];
    }
    tab1[(size_t)v * 256 + g] = a1;
    tab2[(size_t)v * 256 + g] = a2;
}

// ---------------------------------------------------------------------------
// Main recurrence. One block (256 threads) per batch row b.
// wave w = gate type (i,f,g,o), lane l = hidden unit. gate index = tid.
// Whh row cached in 64 VGPRs per lane; h exchanged via per-wave LDS buffer;
// activated gates exchanged via double-buffered LDS, 1 barrier per step.
// ---------------------------------------------------------------------------
__launch_bounds__(256, 4)
__global__ void lstm_main(const int*   __restrict__ s1,
                          const int*   __restrict__ s2,
                          const int*   __restrict__ len1,
                          const int*   __restrict__ len2,
                          const float* __restrict__ tab1,
                          const float* __restrict__ tab2,
                          const float* __restrict__ Whh1,
                          const float* __restrict__ Whh2,
                          const float* __restrict__ Wl1,
                          const float* __restrict__ bl1,
                          const float* __restrict__ Wl2,
                          const float* __restrict__ bl2,
                          float* __restrict__ out) {
    const int b   = blockIdx.x;
    const int tid = threadIdx.x;
    const int w   = tid >> 6;            // wave id = gate type
    const int l   = tid & 63;            // hidden unit
    const int gi  = tid;                 // gate index = 64*w + l

    __shared__ __align__(16) float hbuf[4][2][Hh];  // per-wave h, double buffered
    __shared__ float gbuf[2][256];                  // activated gates, double buffered
    __shared__ __align__(16) float h2s[Hh];
    __shared__ float ys[128];

    // activation constants: waves 0,1,3 -> sigmoid; wave 2 -> tanh = 2*sig(2x)-1
    const float m  = (w == 2) ? 2.0f : 1.0f;
    const float Am = (w == 2) ? 2.0f : 1.0f;
    const float Bc = (w == 2) ? -1.0f : 0.0f;

    float wreg[64];
    float c = 0.0f, h_init = 0.0f;

    for (int phase = 0; phase < 2; ++phase) {
        const int*   sent = phase ? (s2 + (size_t)b * Tt) : (s1 + (size_t)b * Tt);
        const float* tab  = phase ? tab2 : tab1;
        const float* Whh  = phase ? Whh2 : Whh1;
        const int*   lenp = phase ? (len2 + (size_t)b * Hh) : (len1 + (size_t)b * Hh);

        // cache my Whh row (64 floats) in registers
        const float* wp = Whh + (size_t)gi * Hh;
#pragma unroll
        for (int j = 0; j < 16; ++j) {
            const float4 t4 = *(const float4*)(wp + 4 * j);
            wreg[4 * j + 0] = t4.x;
            wreg[4 * j + 1] = t4.y;
            wreg[4 * j + 2] = t4.z;
            wreg[4 * j + 3] = t4.w;
        }
        const int myidx = lenp[l];

        hbuf[w][0][l] = h_init;          // wave-local init
        float selh = 0.0f, selc = 0.0f;

        // token / table-row software pipeline (2 steps ahead)
        const int t0 = sent[0];
        const int t1 = sent[1];
        int tok_nn   = sent[2];
        float xw_cur = tab[(size_t)t0 * 256 + gi];
        float xw_nxt = tab[(size_t)t1 * 256 + gi];

        auto step = [&](int t, int rb, int wb2) {
            // issue future loads: xw for t+2, token for t+3
            const float xw_fut = tab[(size_t)tok_nn * 256 + gi];
            const int   nidx   = (t + 3 < Tt) ? (t + 3) : (Tt - 1);
            const int   tok_fut = sent[nidx];

            // GEMV: gate = xw + sum_k h[k] * Whh[gi][k]
            const float4* h4 = (const float4*)hbuf[w][rb];
            float a0 = xw_cur, a1 = 0.0f, a2 = 0.0f, a3 = 0.0f;
#pragma unroll
            for (int kk = 0; kk < 16; ++kk) {
                const float4 hv = h4[kk];   // broadcast read
                a0 += hv.x * wreg[4 * kk + 0];
                a1 += hv.y * wreg[4 * kk + 1];
                a2 += hv.z * wreg[4 * kk + 2];
                a3 += hv.w * wreg[4 * kk + 3];
            }
            const float acc = (a0 + a1) + (a2 + a3);

            // activation (branch-free sigmoid/tanh select per wave)
            const float sg  = 1.0f / (1.0f + __expf(-m * acc));
            gbuf[rb][gi] = Am * sg + Bc;
            __syncthreads();

            // redundant c/h update in every wave (no second barrier needed)
            const float iv = gbuf[rb][l];
            const float fv = gbuf[rb][64 + l];
            const float gv = gbuf[rb][128 + l];
            const float ov = gbuf[rb][192 + l];
            c = fv * c + iv * gv;
            const float th = 2.0f / (1.0f + __expf(-2.0f * c)) - 1.0f;
            const float h  = ov * th;

            const bool hit = (t == myidx);
            selh = hit ? h : selh;
            selc = hit ? c : selc;

            hbuf[w][wb2][l] = h;            // wave-local write for next step

            // rotate pipeline
            xw_cur = xw_nxt;
            xw_nxt = xw_fut;
            tok_nn = tok_fut;
        };

        for (int t = 0; t < Tt; t += 2) {
            step(t,     0, 1);
            step(t + 1, 1, 0);
        }

        c = selc;        // LSTM2 init / final gathered state
        h_init = selh;
    }

    // ---------------- epilogue MLP: tanh(h2 @ Wl1.T + bl1) @ Wl2.T + bl2 ----
    if (w == 0) h2s[l] = h_init;
    __syncthreads();
    if (tid < 128) {
        float acc = bl1[tid];
        const float* wl = Wl1 + (size_t)tid * 64;
#pragma unroll
        for (int k = 0; k < 64; ++k) acc += h2s[k] * wl[k];
        const float sg = 1.0f / (1.0f + __expf(-2.0f * acc));
        ys[tid] = 2.0f * sg - 1.0f;
    }
    __syncthreads();
    if (tid < 4) {
        float acc = bl2[tid];
        const float* wl = Wl2 + (size_t)tid * 128;
#pragma unroll
        for (int k = 0; k < 128; ++k) acc += ys[k] * wl[k];
        out[(size_t)b * 4 + tid] = acc;
    }
}

// ---------------------------------------------------------------------------
extern "C" void kernel_launch(void* const* d_in, const int* in_sizes, int n_in,
                              void* d_out, int out_size, void* d_ws, size_t ws_size,
                              hipStream_t stream) {
    const int*   s1   = (const int*)d_in[0];
    const int*   s2   = (const int*)d_in[1];
    const int*   l1   = (const int*)d_in[2];
    const int*   l2   = (const int*)d_in[3];
    // d_in[4], d_in[5] (s1_s, s2_s) unused by the reference
    const float* emb  = (const float*)d_in[6];
    const float* Wih1 = (const float*)d_in[7];
    const float* Whh1 = (const float*)d_in[8];
    const float* bih1 = (const float*)d_in[9];
    const float* bhh1 = (const float*)d_in[10];
    const float* Wih2 = (const float*)d_in[11];
    const float* Whh2 = (const float*)d_in[12];
    const float* bih2 = (const float*)d_in[13];
    const float* bhh2 = (const float*)d_in[14];
    const float* Wl1  = (const float*)d_in[15];
    const float* bl1  = (const float*)d_in[16];
    const float* Wl2  = (const float*)d_in[17];
    const float* bl2  = (const float*)d_in[18];
    float* out = (float*)d_out;

    float* tab1 = (float*)d_ws;                       // [V,256] fp32
    float* tab2 = tab1 + (size_t)Vv * 256;            // [V,256] fp32  (total 65.6 MB)

    build_tables<<<Vv, 256, 0, stream>>>(emb, Wih1, bih1, bhh1,
                                         Wih2, bih2, bhh2, tab1, tab2);
    lstm_main<<<Bsz, 256, 0, stream>>>(s1, s2, l1, l2, tab1, tab2,
                                       Whh1, Whh2, Wl1, bl1, Wl2, bl2, out);
}